// Round 1
// baseline (101.193 us; speedup 1.0000x reference)
//
#include <hip/hip_runtime.h>

// MomentAccumulatorObserver: scatter (permutation) -> gather-products -> add carry.
// N_NODES = 1e6, N_EDGES = 8e6. All stages memory-bound.

__global__ void scatter_kernel(const float* __restrict__ vals,
                               const int* __restrict__ sidx,
                               float* __restrict__ flat, int n) {
    int i = blockIdx.x * blockDim.x + threadIdx.x;
    if (i < n) flat[sidx[i]] = vals[i];
}

__global__ void mem1_kernel(const float* __restrict__ flat,
                            const int* __restrict__ ms1,
                            const float* __restrict__ carry1,
                            float* __restrict__ out1, int n) {
    int i = blockIdx.x * blockDim.x + threadIdx.x;
    if (i < n) out1[i] = carry1[i] + flat[ms1[i]];
}

__global__ void mem2_kernel(const float* __restrict__ flat,
                            const int2* __restrict__ ms2,
                            const float* __restrict__ carry2,
                            float* __restrict__ out2, int n) {
    int i = blockIdx.x * blockDim.x + threadIdx.x;
    if (i < n) {
        int2 p = ms2[i];
        out2[i] = carry2[i] + flat[p.x] * flat[p.y];
    }
}

extern "C" void kernel_launch(void* const* d_in, const int* in_sizes, int n_in,
                              void* d_out, int out_size, void* d_ws, size_t ws_size,
                              hipStream_t stream) {
    const float* sampled   = (const float*)d_in[0];
    const int*   sidx      = (const int*)d_in[1];
    const int*   ms1       = (const int*)d_in[2];
    const int2*  ms2       = (const int2*)d_in[3];
    const float* carry1    = (const float*)d_in[4];
    const float* carry2    = (const float*)d_in[5];

    const int n_nodes = in_sizes[0];          // 1,000,000
    const int n_edges = in_sizes[5];          // 8,000,000

    float* flat = (float*)d_ws;               // 4 MB scratch, fully written by scatter
    float* out1 = (float*)d_out;              // [n_nodes]
    float* out2 = out1 + n_nodes;             // [n_edges]

    const int B = 256;
    // Stage 1: permutation scatter builds flat_state. Must complete first
    // (same-stream ordering guarantees it).
    scatter_kernel<<<(n_nodes + B - 1) / B, B, 0, stream>>>(sampled, sidx, flat, n_nodes);
    // Stage 2: singleton moments (ms1 is arange -> coalesced gather).
    mem1_kernel<<<(n_nodes + B - 1) / B, B, 0, stream>>>(flat, ms1, carry1, out1, n_nodes);
    // Stage 3: pair moments (random gathers into 4 MB table; L2/LLC-resident).
    mem2_kernel<<<(n_edges + B - 1) / B, B, 0, stream>>>(flat, ms2, carry2, out2, n_edges);
}